// Round 1
// baseline (560.495 us; speedup 1.0000x reference)
//
#include <hip/hip_runtime.h>
#include <hip/hip_bf16.h>

#define N 8192
#define IN_C 256
#define OUT_C 64
#define ALPHA 0.2f

typedef short bf16x8 __attribute__((ext_vector_type(8)));
typedef float f32x4 __attribute__((ext_vector_type(4)));

// ---- ws layout (bytes) ----
#define OFF_H      0u            // f32  [8192][64]   h = x@w
#define OFF_HT     2097152u      // bf16 [64][8192]   h transposed
#define OFF_FS     3145728u      // f32  [8192]       f_src
#define OFF_FD     3178496u      // f32  [8192]       f_dst
#define OFF_FDMAX  3211264u      // f32  [1]
#define OFF_NUM    3211520u      // f32  [4][8192][64] partial numerators
#define OFF_DEN    11600128u     // f32  [4][8192]     partial denominators

// ---------------- h = x @ w ----------------
__global__ __launch_bounds__(256) void k_linear(const float* __restrict__ x,
                                                const float* __restrict__ w,
                                                float* __restrict__ h) {
    __shared__ float wl[IN_C * OUT_C];
    int t = threadIdx.x;
    for (int idx = t; idx < IN_C * OUT_C; idx += 256) wl[idx] = w[idx];
    __syncthreads();
    int i = blockIdx.x * 4 + (t >> 6);
    int c = t & 63;
    const float* xr = x + (size_t)i * IN_C;
    float acc = 0.f;
#pragma unroll 8
    for (int k = 0; k < IN_C; ++k) acc = fmaf(xr[k], wl[k * 64 + c], acc);
    h[(size_t)i * 64 + c] = acc;
}

// ---------------- h_t[c][i] = bf16(h[i][c]) ----------------
__global__ __launch_bounds__(256) void k_tr(const float* __restrict__ h,
                                            __hip_bfloat16* __restrict__ ht) {
    __shared__ __hip_bfloat16 lds[64 * 65];
    int t = threadIdx.x;
    int i0 = blockIdx.x * 64;
#pragma unroll
    for (int k = 0; k < 16; ++k) {
        int idx = k * 256 + t;
        int il = idx >> 6, c = idx & 63;          // read h[i0+il][c], coalesced in c
        lds[c * 65 + il] = __float2bfloat16(h[(size_t)(i0 + il) * 64 + c]);
    }
    __syncthreads();
#pragma unroll
    for (int k = 0; k < 16; ++k) {
        int idx = k * 256 + t;
        int c = idx >> 6, il = idx & 63;          // write ht[c][i0+il], coalesced in il
        ht[(size_t)c * N + i0 + il] = lds[c * 65 + il];
    }
}

// ---------------- f_src, f_dst ----------------
__global__ __launch_bounds__(256) void k_f(const float* __restrict__ h,
                                           const float* __restrict__ a,
                                           float* __restrict__ fs,
                                           float* __restrict__ fd) {
    int t = threadIdx.x;
    int lane = t & 63;
    int i = blockIdx.x * 4 + (t >> 6);
    float v = h[(size_t)i * 64 + lane];
    float s = v * a[lane];
    float d = v * a[64 + lane];
#pragma unroll
    for (int off = 32; off > 0; off >>= 1) {
        s += __shfl_xor(s, off, 64);
        d += __shfl_xor(d, off, 64);
    }
    if (lane == 0) { fs[i] = s; fd[i] = d; }
}

// ---------------- fd_max = max_j f_dst[j] ----------------
__global__ __launch_bounds__(256) void k_fdmax(const float* __restrict__ fd,
                                               float* __restrict__ out) {
    __shared__ float red[256];
    int t = threadIdx.x;
    float m = -3.4e38f;
    for (int j = t; j < N; j += 256) m = fmaxf(m, fd[j]);
    red[t] = m;
    __syncthreads();
    for (int s = 128; s > 0; s >>= 1) {
        if (t < s) red[t] = fmaxf(red[t], red[t + s]);
        __syncthreads();
    }
    if (t == 0) out[0] = red[0];
}

// ---------------- main: num += (W o A) @ h, den += rowsum ----------------
// grid 512: block = (row-block rb of 64 rows) x (K-quarter kq of 2048 j)
// 4 waves/block, wave owns 16 rows; mfma_f32_16x16x32_bf16
// A-frag: lane l holds W[row = l&15][k = (l>>4)*8 + e]   (computed on the fly)
// B-frag: lane l holds h[k = (l>>4)*8 + e][col = ct*16 + (l&15)]  (from h_t, contiguous)
// D:      col = l&15, row = (l>>4)*4 + reg               (m89-verified)
__global__ __launch_bounds__(256, 2) void k_main(
    const int* __restrict__ adj,
    const float* __restrict__ fsrc,
    const float* __restrict__ fdst,
    const float* __restrict__ fdmax_p,
    const unsigned short* __restrict__ ht,
    float* __restrict__ nump,
    float* __restrict__ denp_out) {
    int bid = blockIdx.x;
    int rb = bid >> 2;      // 0..127
    int kq = bid & 3;       // 0..3
    int t = threadIdx.x;
    int wave = t >> 6;
    int lane = t & 63;
    int r  = lane & 15;
    int kg = lane >> 4;
    int i  = rb * 64 + wave * 16 + r;     // this lane's A row
    int j0 = kq * 2048;

    float fs  = fsrc[i];
    float fdm = *fdmax_p;
    float e0  = fs + fdm;
    float m   = fmaxf(e0, ALPHA * e0);    // global upper bound of this row's exponent

    const int* arow = adj + (size_t)i * N;
    f32x4 acc0 = {0.f, 0.f, 0.f, 0.f};
    f32x4 acc1 = {0.f, 0.f, 0.f, 0.f};
    f32x4 acc2 = {0.f, 0.f, 0.f, 0.f};
    f32x4 acc3 = {0.f, 0.f, 0.f, 0.f};
    float dacc = 0.f;

#pragma unroll 2
    for (int ks = 0; ks < 64; ++ks) {
        int jb = j0 + ks * 32 + kg * 8;   // this lane's 8 consecutive k (=j) positions
        int4   ad0 = *(const int4*)(arow + jb);
        int4   ad1 = *(const int4*)(arow + jb + 4);
        float4 fd0 = *(const float4*)(fdst + jb);
        float4 fd1 = *(const float4*)(fdst + jb + 4);
        bf16x8 b0 = *(const bf16x8*)(ht + (size_t)(0 * 16 + r) * N + jb);
        bf16x8 b1 = *(const bf16x8*)(ht + (size_t)(1 * 16 + r) * N + jb);
        bf16x8 b2 = *(const bf16x8*)(ht + (size_t)(2 * 16 + r) * N + jb);
        bf16x8 b3 = *(const bf16x8*)(ht + (size_t)(3 * 16 + r) * N + jb);

        int   ad[8]  = {ad0.x, ad0.y, ad0.z, ad0.w, ad1.x, ad1.y, ad1.z, ad1.w};
        float fdv[8] = {fd0.x, fd0.y, fd0.z, fd0.w, fd1.x, fd1.y, fd1.z, fd1.w};
        bf16x8 af;
#pragma unroll
        for (int e = 0; e < 8; ++e) {
            float ee = fs + fdv[e];
            float l  = fmaxf(ee, ALPHA * ee);             // leaky-relu
            float wt = (ad[e] > 0) ? __expf(l - m) : 0.f; // in [0,1]
            dacc += wt;
            union { float f; unsigned u; } cv; cv.f = wt; // f32 -> bf16 RNE
            unsigned ru = cv.u + 0x7FFF + ((cv.u >> 16) & 1);
            af[e] = (short)(ru >> 16);
        }
        acc0 = __builtin_amdgcn_mfma_f32_16x16x32_bf16(af, b0, acc0, 0, 0, 0);
        acc1 = __builtin_amdgcn_mfma_f32_16x16x32_bf16(af, b1, acc1, 0, 0, 0);
        acc2 = __builtin_amdgcn_mfma_f32_16x16x32_bf16(af, b2, acc2, 0, 0, 0);
        acc3 = __builtin_amdgcn_mfma_f32_16x16x32_bf16(af, b3, acc3, 0, 0, 0);
    }

    // denominator: reduce the 4 k-groups holding the same row
    dacc += __shfl_xor(dacc, 16, 64);
    dacc += __shfl_xor(dacc, 32, 64);
    if (kg == 0) denp_out[kq * N + i] = dacc;

    // numerator partials: D layout col=lane&15, row=(lane>>4)*4+reg
    int orow = rb * 64 + wave * 16 + kg * 4;
    float* np = nump + (size_t)kq * N * 64;
#pragma unroll
    for (int rr = 0; rr < 4; ++rr) {
        np[(size_t)(orow + rr) * 64 + 0 * 16 + r] = acc0[rr];
        np[(size_t)(orow + rr) * 64 + 1 * 16 + r] = acc1[rr];
        np[(size_t)(orow + rr) * 64 + 2 * 16 + r] = acc2[rr];
        np[(size_t)(orow + rr) * 64 + 3 * 16 + r] = acc3[rr];
    }
}

// ---------------- out = elu(num/den) ----------------
__global__ __launch_bounds__(256) void k_final(const float* __restrict__ nump,
                                               const float* __restrict__ denp,
                                               float* __restrict__ out) {
    int gid = blockIdx.x * 256 + threadIdx.x;   // 0 .. 524287
    int i = gid >> 6;
    float num = nump[gid] + nump[524288 + gid] + nump[2 * 524288 + gid] + nump[3 * 524288 + gid];
    float den = denp[i] + denp[N + i] + denp[2 * N + i] + denp[3 * N + i];
    float v = num / den;
    out[gid] = v > 0.f ? v : __expf(v) - 1.f;
}

extern "C" void kernel_launch(void* const* d_in, const int* in_sizes, int n_in,
                              void* d_out, int out_size, void* d_ws, size_t ws_size,
                              hipStream_t stream) {
    const float* x   = (const float*)d_in[0];
    const int*   adj = (const int*)d_in[1];
    const float* w   = (const float*)d_in[2];
    const float* a   = (const float*)d_in[3];
    float* out = (float*)d_out;
    char*  ws  = (char*)d_ws;

    float*          h    = (float*)(ws + OFF_H);
    __hip_bfloat16* ht   = (__hip_bfloat16*)(ws + OFF_HT);
    float*          fs   = (float*)(ws + OFF_FS);
    float*          fd   = (float*)(ws + OFF_FD);
    float*          fdm  = (float*)(ws + OFF_FDMAX);
    float*          nump = (float*)(ws + OFF_NUM);
    float*          denp = (float*)(ws + OFF_DEN);

    k_linear<<<2048, 256, 0, stream>>>(x, w, h);
    k_tr<<<128, 256, 0, stream>>>(h, ht);
    k_f<<<2048, 256, 0, stream>>>(h, a, fs, fd);
    k_fdmax<<<1, 256, 0, stream>>>(fd, fdm);
    k_main<<<512, 256, 0, stream>>>(adj, fs, fd, fdm, (const unsigned short*)ht, nump, denp);
    k_final<<<2048, 256, 0, stream>>>(nump, denp, out);
}

// Round 2
// 469.942 us; speedup vs baseline: 1.1927x; 1.1927x over previous
//
#include <hip/hip_runtime.h>
#include <hip/hip_bf16.h>

#define N 8192
#define IN_C 256
#define OUT_C 64
#define ALPHA 0.2f

typedef short bf16x8 __attribute__((ext_vector_type(8)));
typedef float f32x4 __attribute__((ext_vector_type(4)));

// ---- ws layout (bytes) ----
#define OFF_H      0u            // f32  [8192][64]   h = x@w
#define OFF_HT     2097152u      // bf16 [64][8192]   h transposed
#define OFF_FS     3145728u      // f32  [8192]       f_src
#define OFF_FD     3178496u      // f32  [8192]       f_dst
#define OFF_FDMAX  3211264u      // f32  [1]
#define OFF_NUM    3211520u      // f32  [KQ][8192][64] partial numerators, den follows

// ---------------- h = x @ w  (+ fused f_src/f_dst) ----------------
__global__ __launch_bounds__(256) void k_linear(const float* __restrict__ x,
                                                const float* __restrict__ w,
                                                const float* __restrict__ a,
                                                float* __restrict__ h,
                                                float* __restrict__ fs,
                                                float* __restrict__ fd) {
    __shared__ float wl[IN_C * OUT_C];
    int t = threadIdx.x;
    for (int idx = t; idx < IN_C * OUT_C; idx += 256) wl[idx] = w[idx];
    __syncthreads();
    int i = blockIdx.x * 4 + (t >> 6);
    int c = t & 63;
    const float* xr = x + (size_t)i * IN_C;
    float acc = 0.f;
#pragma unroll 8
    for (int k = 0; k < IN_C; ++k) acc = fmaf(xr[k], wl[k * 64 + c], acc);
    h[(size_t)i * 64 + c] = acc;
    // fused: f_src[i] = sum_c h[i][c]*a[c], f_dst[i] = sum_c h[i][c]*a[64+c]
    float s = acc * a[c];
    float d = acc * a[64 + c];
#pragma unroll
    for (int off = 32; off > 0; off >>= 1) {
        s += __shfl_xor(s, off, 64);
        d += __shfl_xor(d, off, 64);
    }
    if (c == 0) { fs[i] = s; fd[i] = d; }
}

// ---------------- h_t[c][i] = bf16(h[i][c]) ----------------
__global__ __launch_bounds__(256) void k_tr(const float* __restrict__ h,
                                            __hip_bfloat16* __restrict__ ht) {
    __shared__ __hip_bfloat16 lds[64 * 65];
    int t = threadIdx.x;
    int i0 = blockIdx.x * 64;
#pragma unroll
    for (int k = 0; k < 16; ++k) {
        int idx = k * 256 + t;
        int il = idx >> 6, c = idx & 63;
        lds[c * 65 + il] = __float2bfloat16(h[(size_t)(i0 + il) * 64 + c]);
    }
    __syncthreads();
#pragma unroll
    for (int k = 0; k < 16; ++k) {
        int idx = k * 256 + t;
        int c = idx >> 6, il = idx & 63;
        ht[(size_t)c * N + i0 + il] = lds[c * 65 + il];
    }
}

// ---------------- fd_max = max_j f_dst[j] ----------------
__global__ __launch_bounds__(256) void k_fdmax(const float* __restrict__ fd,
                                               float* __restrict__ out) {
    __shared__ float red[256];
    int t = threadIdx.x;
    float m = -3.4e38f;
    for (int j = t; j < N; j += 256) m = fmaxf(m, fd[j]);
    red[t] = m;
    __syncthreads();
    for (int s = 128; s > 0; s >>= 1) {
        if (t < s) red[t] = fmaxf(red[t], red[t + s]);
        __syncthreads();
    }
    if (t == 0) out[0] = red[0];
}

// ---------------- main kernel ----------------
// grid = KQ*128 blocks; bid = kq*128 + rb. Block: 64 rows x (N/KQ) cols of A.
// 4 waves, wave owns 16 rows; mfma_f32_16x16x32_bf16.
// A-frag lane l: W[row=l&15][k=(l>>4)*8+e] generated on the fly.
// B-frag lane l: h[k][col] read from ht (contiguous 16B).
// Explicit 2-deep software pipeline (Stage A/B) so a full stage of loads
// stays in flight during each compute (fixes the VGPR=32 serialization).
struct Stage {
    int4   ad0, ad1;
    float4 fd0, fd1;
    bf16x8 b0, b1, b2, b3;
};

__device__ __forceinline__ void load_stage(Stage& s,
        const int* __restrict__ arow, const float* __restrict__ fdst,
        const unsigned short* __restrict__ pb0, const unsigned short* __restrict__ pb1,
        const unsigned short* __restrict__ pb2, const unsigned short* __restrict__ pb3,
        int jb) {
    s.ad0 = *(const int4*)(arow + jb);
    s.ad1 = *(const int4*)(arow + jb + 4);
    s.fd0 = *(const float4*)(fdst + jb);
    s.fd1 = *(const float4*)(fdst + jb + 4);
    s.b0  = *(const bf16x8*)(pb0 + jb);
    s.b1  = *(const bf16x8*)(pb1 + jb);
    s.b2  = *(const bf16x8*)(pb2 + jb);
    s.b3  = *(const bf16x8*)(pb3 + jb);
}

__device__ __forceinline__ void compute_stage(const Stage& s, float fs, float m,
        float& dacc, f32x4& acc0, f32x4& acc1, f32x4& acc2, f32x4& acc3) {
    int   ad[8]  = {s.ad0.x, s.ad0.y, s.ad0.z, s.ad0.w, s.ad1.x, s.ad1.y, s.ad1.z, s.ad1.w};
    float fdv[8] = {s.fd0.x, s.fd0.y, s.fd0.z, s.fd0.w, s.fd1.x, s.fd1.y, s.fd1.z, s.fd1.w};
    bf16x8 af;
#pragma unroll
    for (int e = 0; e < 8; ++e) {
        float ee = fs + fdv[e];
        float l  = fmaxf(ee, ALPHA * ee);             // leaky-relu
        float wt = (ad[e] > 0) ? __expf(l - m) : 0.f; // in [0,1]
        dacc += wt;
        union { float f; unsigned u; } cv; cv.f = wt; // f32 -> bf16 RNE
        unsigned ru = cv.u + 0x7FFF + ((cv.u >> 16) & 1);
        af[e] = (short)(ru >> 16);
    }
    acc0 = __builtin_amdgcn_mfma_f32_16x16x32_bf16(af, s.b0, acc0, 0, 0, 0);
    acc1 = __builtin_amdgcn_mfma_f32_16x16x32_bf16(af, s.b1, acc1, 0, 0, 0);
    acc2 = __builtin_amdgcn_mfma_f32_16x16x32_bf16(af, s.b2, acc2, 0, 0, 0);
    acc3 = __builtin_amdgcn_mfma_f32_16x16x32_bf16(af, s.b3, acc3, 0, 0, 0);
}

__global__ __launch_bounds__(256) void k_main(
    const int* __restrict__ adj,
    const float* __restrict__ fsrc,
    const float* __restrict__ fdst,
    const float* __restrict__ fdmax_p,
    const unsigned short* __restrict__ ht,
    float* __restrict__ nump,
    float* __restrict__ denp_out,
    int jch, int ns) {
    int bid = blockIdx.x;
    int rb = bid & 127;
    int kq = bid >> 7;
    int t = threadIdx.x;
    int wave = t >> 6;
    int lane = t & 63;
    int r  = lane & 15;
    int kg = lane >> 4;
    int i  = rb * 64 + wave * 16 + r;
    int j0 = kq * jch;

    float fs  = fsrc[i];
    float fdm = *fdmax_p;
    float e0  = fs + fdm;
    float m   = fmaxf(e0, ALPHA * e0);   // valid row-wise softmax shift (monotone in fd)

    const int* arow = adj + (size_t)i * N;
    const unsigned short* pb0 = ht + (size_t)(r)      * N;
    const unsigned short* pb1 = ht + (size_t)(16 + r) * N;
    const unsigned short* pb2 = ht + (size_t)(32 + r) * N;
    const unsigned short* pb3 = ht + (size_t)(48 + r) * N;

    f32x4 acc0 = {0.f,0.f,0.f,0.f}, acc1 = {0.f,0.f,0.f,0.f};
    f32x4 acc2 = {0.f,0.f,0.f,0.f}, acc3 = {0.f,0.f,0.f,0.f};
    float dacc = 0.f;

    int base = j0 + kg * 8;
    Stage A, B;
    load_stage(A, arow, fdst, pb0, pb1, pb2, pb3, base);
    load_stage(B, arow, fdst, pb0, pb1, pb2, pb3, base + 32);

#pragma unroll 1
    for (int ks = 0; ks < ns - 2; ks += 2) {
        compute_stage(A, fs, m, dacc, acc0, acc1, acc2, acc3);
        load_stage(A, arow, fdst, pb0, pb1, pb2, pb3, base + (ks + 2) * 32);
        compute_stage(B, fs, m, dacc, acc0, acc1, acc2, acc3);
        load_stage(B, arow, fdst, pb0, pb1, pb2, pb3, base + (ks + 3) * 32);
    }
    compute_stage(A, fs, m, dacc, acc0, acc1, acc2, acc3);
    compute_stage(B, fs, m, dacc, acc0, acc1, acc2, acc3);

    // denominator: reduce the 4 k-groups holding the same row
    dacc += __shfl_xor(dacc, 16, 64);
    dacc += __shfl_xor(dacc, 32, 64);
    if (kg == 0) denp_out[kq * N + i] = dacc;

    // numerator partials: D layout col=lane&15, row=(lane>>4)*4+reg
    int orow = rb * 64 + wave * 16 + kg * 4;
    float* np = nump + (size_t)kq * N * 64;
#pragma unroll
    for (int rr = 0; rr < 4; ++rr) {
        np[(size_t)(orow + rr) * 64 + 0 * 16 + r] = acc0[rr];
        np[(size_t)(orow + rr) * 64 + 1 * 16 + r] = acc1[rr];
        np[(size_t)(orow + rr) * 64 + 2 * 16 + r] = acc2[rr];
        np[(size_t)(orow + rr) * 64 + 3 * 16 + r] = acc3[rr];
    }
}

// ---------------- out = elu(num/den) ----------------
__global__ __launch_bounds__(256) void k_final(const float* __restrict__ nump,
                                               const float* __restrict__ denp,
                                               float* __restrict__ out,
                                               int kqn) {
    int gid = blockIdx.x * 256 + threadIdx.x;   // 0 .. 524287
    int i = gid >> 6;
    float num = 0.f, den = 0.f;
    for (int q = 0; q < kqn; ++q) {
        num += nump[(size_t)q * (N * 64) + gid];
        den += denp[q * N + i];
    }
    float v = num / den;
    out[gid] = v > 0.f ? v : __expf(v) - 1.f;
}

extern "C" void kernel_launch(void* const* d_in, const int* in_sizes, int n_in,
                              void* d_out, int out_size, void* d_ws, size_t ws_size,
                              hipStream_t stream) {
    const float* x   = (const float*)d_in[0];
    const int*   adj = (const int*)d_in[1];
    const float* w   = (const float*)d_in[2];
    const float* a   = (const float*)d_in[3];
    float* out = (float*)d_out;
    char*  ws  = (char*)d_ws;

    float*          h    = (float*)(ws + OFF_H);
    __hip_bfloat16* ht   = (__hip_bfloat16*)(ws + OFF_HT);
    float*          fs   = (float*)(ws + OFF_FS);
    float*          fd   = (float*)(ws + OFF_FD);
    float*          fdm  = (float*)(ws + OFF_FDMAX);
    float*          nump = (float*)(ws + OFF_NUM);

    // pick K-split by what the workspace can hold (8 preferred for TLP)
    size_t need8 = (size_t)OFF_NUM + 8ull * N * 64 * 4 + 8ull * N * 4;
    int KQ = (ws_size >= need8) ? 8 : 4;
    float* denp = nump + (size_t)KQ * N * 64;
    int jch = N / KQ;
    int ns  = jch / 32;

    k_linear<<<2048, 256, 0, stream>>>(x, w, a, h, fs, fd);
    k_tr<<<128, 256, 0, stream>>>(h, ht);
    k_fdmax<<<1, 256, 0, stream>>>(fd, fdm);
    k_main<<<KQ * 128, 256, 0, stream>>>(adj, fs, fd, fdm,
                                         (const unsigned short*)ht, nump, denp, jch, ns);
    k_final<<<2048, 256, 0, stream>>>(nump, denp, out, KQ);
}

// Round 4
// 468.696 us; speedup vs baseline: 1.1959x; 1.0027x over previous
//
#include <hip/hip_runtime.h>
#include <hip/hip_bf16.h>

#define N 8192
#define IN_C 256
#define OUT_C 64
#define ALPHA 0.2f
#define L2E 1.44269504f

typedef short bf16x8 __attribute__((ext_vector_type(8)));
typedef float f32x4 __attribute__((ext_vector_type(4)));

// ---- ws layout (bytes) ----
#define OFF_H      0u            // f32  [8192][64]   h = x@w
#define OFF_HT     2097152u      // bf16 [64][8192]   h transposed
#define OFF_FS     3145728u      // f32  [8192]       f_src
#define OFF_FD     3178496u      // f32  [8192]       f_dst
#define OFF_FDMAX  3211264u      // f32  [1]
#define OFF_NUM    3211520u      // f32  [KQ][8192][64] partial numerators, den follows

// ---------------- h = x @ w  (+ fused f_src/f_dst) ----------------
__global__ __launch_bounds__(256) void k_linear(const float* __restrict__ x,
                                                const float* __restrict__ w,
                                                const float* __restrict__ a,
                                                float* __restrict__ h,
                                                float* __restrict__ fs,
                                                float* __restrict__ fd) {
    __shared__ float wl[IN_C * OUT_C];
    int t = threadIdx.x;
    for (int idx = t; idx < IN_C * OUT_C; idx += 256) wl[idx] = w[idx];
    __syncthreads();
    int i = blockIdx.x * 4 + (t >> 6);
    int c = t & 63;
    const float* xr = x + (size_t)i * IN_C;
    float acc = 0.f;
#pragma unroll 8
    for (int k = 0; k < IN_C; ++k) acc = fmaf(xr[k], wl[k * 64 + c], acc);
    h[(size_t)i * 64 + c] = acc;
    float s = acc * a[c];
    float d = acc * a[64 + c];
#pragma unroll
    for (int off = 32; off > 0; off >>= 1) {
        s += __shfl_xor(s, off, 64);
        d += __shfl_xor(d, off, 64);
    }
    if (c == 0) { fs[i] = s; fd[i] = d; }
}

// ---------------- h_t[c][i] = bf16(h[i][c]) ----------------
__global__ __launch_bounds__(256) void k_tr(const float* __restrict__ h,
                                            __hip_bfloat16* __restrict__ ht) {
    __shared__ __hip_bfloat16 lds[64 * 65];
    int t = threadIdx.x;
    int i0 = blockIdx.x * 64;
#pragma unroll
    for (int k = 0; k < 16; ++k) {
        int idx = k * 256 + t;
        int il = idx >> 6, c = idx & 63;
        lds[c * 65 + il] = __float2bfloat16(h[(size_t)(i0 + il) * 64 + c]);
    }
    __syncthreads();
#pragma unroll
    for (int k = 0; k < 16; ++k) {
        int idx = k * 256 + t;
        int c = idx >> 6, il = idx & 63;
        ht[(size_t)c * N + i0 + il] = lds[c * 65 + il];
    }
}

// ---------------- fd_max = max_j f_dst[j] ----------------
__global__ __launch_bounds__(256) void k_fdmax(const float* __restrict__ fd,
                                               float* __restrict__ out) {
    __shared__ float red[256];
    int t = threadIdx.x;
    float m = -3.4e38f;
    for (int j = t; j < N; j += 256) m = fmaxf(m, fd[j]);
    red[t] = m;
    __syncthreads();
    for (int s = 128; s > 0; s >>= 1) {
        if (t < s) red[t] = fmaxf(red[t], red[t + s]);
        __syncthreads();
    }
    if (t == 0) out[0] = red[0];
}

// ---------------- main kernel ----------------
// grid = KQ*128; bid = kq*128 + rb. Block: 64 rows x (N/KQ) j-cols.
// 4 waves, wave owns 16 rows; mfma_f32_16x16x32_bf16.
// A-frag lane l: W[row=l&15][k=(l>>4)*8+e] generated on the fly from adj+fdst.
// Denominator comes from a 5th MFMA vs an all-ones bf16 B (den = (W.A)@1),
// so it is bit-consistent with the numerator's bf16 weights.
struct Stage {
    int4   ad0, ad1;
    float4 fd0, fd1;
    bf16x8 b0, b1, b2, b3;
};

__device__ __forceinline__ void load_stage(Stage& s,
        const int* __restrict__ arow, const float* __restrict__ fdst,
        const unsigned short* __restrict__ pb0, const unsigned short* __restrict__ pb1,
        const unsigned short* __restrict__ pb2, const unsigned short* __restrict__ pb3,
        int jb) {
    s.ad0 = *(const int4*)(arow + jb);
    s.ad1 = *(const int4*)(arow + jb + 4);
    s.fd0 = *(const float4*)(fdst + jb);
    s.fd1 = *(const float4*)(fdst + jb + 4);
    s.b0  = *(const bf16x8*)(pb0 + jb);
    s.b1  = *(const bf16x8*)(pb1 + jb);
    s.b2  = *(const bf16x8*)(pb2 + jb);
    s.b3  = *(const bf16x8*)(pb3 + jb);
}

__device__ __forceinline__ void compute_stage(const Stage& s, float fs, float mL,
        const bf16x8& bones,
        f32x4& acc0, f32x4& acc1, f32x4& acc2, f32x4& acc3, f32x4& acc4) {
    int   ad[8]  = {s.ad0.x, s.ad0.y, s.ad0.z, s.ad0.w, s.ad1.x, s.ad1.y, s.ad1.z, s.ad1.w};
    float fdv[8] = {s.fd0.x, s.fd0.y, s.fd0.z, s.fd0.w, s.fd1.x, s.fd1.y, s.fd1.z, s.fd1.w};
    bf16x8 af;
#pragma unroll
    for (int e = 0; e < 8; ++e) {
        float ee = fs + fdv[e];
        float l  = fmaxf(ee, ALPHA * ee);          // leaky-relu
        float a2 = __builtin_fmaf(l, L2E, -mL);    // (l - m) * log2(e)
        float wt = __builtin_amdgcn_exp2f(a2);     // in (0, 1]
        wt = (ad[e] > 0) ? wt : 0.f;
        __hip_bfloat16 hb = __float2bfloat16(wt);
        union { __hip_bfloat16 b; short s16; } u; u.b = hb;
        af[e] = u.s16;
    }
    acc0 = __builtin_amdgcn_mfma_f32_16x16x32_bf16(af, s.b0, acc0, 0, 0, 0);
    acc1 = __builtin_amdgcn_mfma_f32_16x16x32_bf16(af, s.b1, acc1, 0, 0, 0);
    acc2 = __builtin_amdgcn_mfma_f32_16x16x32_bf16(af, s.b2, acc2, 0, 0, 0);
    acc3 = __builtin_amdgcn_mfma_f32_16x16x32_bf16(af, s.b3, acc3, 0, 0, 0);
    acc4 = __builtin_amdgcn_mfma_f32_16x16x32_bf16(af, bones, acc4, 0, 0, 0);
}

__global__ __launch_bounds__(256, 4) void k_main(
    const int* __restrict__ adj,
    const float* __restrict__ fsrc,
    const float* __restrict__ fdst,
    const float* __restrict__ fdmax_p,
    const unsigned short* __restrict__ ht,
    float* __restrict__ nump,
    float* __restrict__ denp_out,
    int jch, int ns) {
    int bid = blockIdx.x;
    int rb = bid & 127;
    int kq = bid >> 7;
    int t = threadIdx.x;
    int wave = t >> 6;
    int lane = t & 63;
    int r  = lane & 15;
    int kg = lane >> 4;
    int i  = rb * 64 + wave * 16 + r;
    int j0 = kq * jch;

    float fs  = fsrc[i];
    float fdm = *fdmax_p;
    float e0  = fs + fdm;
    float m   = fmaxf(e0, ALPHA * e0);   // row-wise softmax shift (monotone in fd)
    float mL  = m * L2E;

    const int* arow = adj + (size_t)i * N;
    const unsigned short* pb0 = ht + (size_t)(r)      * N;
    const unsigned short* pb1 = ht + (size_t)(16 + r) * N;
    const unsigned short* pb2 = ht + (size_t)(32 + r) * N;
    const unsigned short* pb3 = ht + (size_t)(48 + r) * N;

    bf16x8 bones;
#pragma unroll
    for (int e = 0; e < 8; ++e) bones[e] = (short)0x3F80;  // bf16 1.0

    f32x4 acc0 = {0.f,0.f,0.f,0.f}, acc1 = {0.f,0.f,0.f,0.f};
    f32x4 acc2 = {0.f,0.f,0.f,0.f}, acc3 = {0.f,0.f,0.f,0.f};
    f32x4 acc4 = {0.f,0.f,0.f,0.f};

    int base = j0 + kg * 8;
    Stage A, B;
    load_stage(A, arow, fdst, pb0, pb1, pb2, pb3, base);
    load_stage(B, arow, fdst, pb0, pb1, pb2, pb3, base + 32);

#pragma unroll 1
    for (int ks = 0; ks < ns - 2; ks += 2) {
        compute_stage(A, fs, mL, bones, acc0, acc1, acc2, acc3, acc4);
        load_stage(A, arow, fdst, pb0, pb1, pb2, pb3, base + (ks + 2) * 32);
        compute_stage(B, fs, mL, bones, acc0, acc1, acc2, acc3, acc4);
        load_stage(B, arow, fdst, pb0, pb1, pb2, pb3, base + (ks + 3) * 32);
    }
    compute_stage(A, fs, mL, bones, acc0, acc1, acc2, acc3, acc4);
    compute_stage(B, fs, mL, bones, acc0, acc1, acc2, acc3, acc4);

    // numerator partials: D layout col=lane&15, row=(lane>>4)*4+reg
    int orow = rb * 64 + wave * 16 + kg * 4;
    float* np = nump + (size_t)kq * N * 64;
#pragma unroll
    for (int rr = 0; rr < 4; ++rr) {
        np[(size_t)(orow + rr) * 64 + 0 * 16 + r] = acc0[rr];
        np[(size_t)(orow + rr) * 64 + 1 * 16 + r] = acc1[rr];
        np[(size_t)(orow + rr) * 64 + 2 * 16 + r] = acc2[rr];
        np[(size_t)(orow + rr) * 64 + 3 * 16 + r] = acc3[rr];
    }
    // denominator: every lane holds den for rows orow..orow+3 in acc4 (all cols equal)
    if (r == 0) {
#pragma unroll
        for (int rr = 0; rr < 4; ++rr) denp_out[kq * N + orow + rr] = acc4[rr];
    }
}

// ---------------- out = elu(num/den), float4 per thread ----------------
__global__ __launch_bounds__(256) void k_final(const float* __restrict__ nump,
                                               const float* __restrict__ denp,
                                               float* __restrict__ out,
                                               int kqn) {
    int gid = blockIdx.x * 256 + threadIdx.x;   // 0 .. 131071
    int base = gid * 4;
    int i = base >> 6;
    float4 num = {0.f, 0.f, 0.f, 0.f};
    float den = 0.f;
    for (int q = 0; q < kqn; ++q) {
        float4 v = *(const float4*)(nump + (size_t)q * (N * 64) + base);
        num.x += v.x; num.y += v.y; num.z += v.z; num.w += v.w;
        den += denp[q * N + i];
    }
    float rd = 1.f / den;
    float4 o;
    o.x = num.x * rd; o.y = num.y * rd; o.z = num.z * rd; o.w = num.w * rd;
    o.x = o.x > 0.f ? o.x : __expf(o.x) - 1.f;
    o.y = o.y > 0.f ? o.y : __expf(o.y) - 1.f;
    o.z = o.z > 0.f ? o.z : __expf(o.z) - 1.f;
    o.w = o.w > 0.f ? o.w : __expf(o.w) - 1.f;
    *(float4*)(out + base) = o;
}

extern "C" void kernel_launch(void* const* d_in, const int* in_sizes, int n_in,
                              void* d_out, int out_size, void* d_ws, size_t ws_size,
                              hipStream_t stream) {
    const float* x   = (const float*)d_in[0];
    const int*   adj = (const int*)d_in[1];
    const float* w   = (const float*)d_in[2];
    const float* a   = (const float*)d_in[3];
    float* out = (float*)d_out;
    char*  ws  = (char*)d_ws;

    float*          h    = (float*)(ws + OFF_H);
    __hip_bfloat16* ht   = (__hip_bfloat16*)(ws + OFF_HT);
    float*          fs   = (float*)(ws + OFF_FS);
    float*          fd   = (float*)(ws + OFF_FD);
    float*          fdm  = (float*)(ws + OFF_FDMAX);
    float*          nump = (float*)(ws + OFF_NUM);

    size_t need8 = (size_t)OFF_NUM + 8ull * N * 64 * 4 + 8ull * N * 4;
    int KQ = (ws_size >= need8) ? 8 : 4;
    float* denp = nump + (size_t)KQ * N * 64;
    int jch = N / KQ;
    int ns  = jch / 32;

    k_linear<<<2048, 256, 0, stream>>>(x, w, a, h, fs, fd);
    k_tr<<<128, 256, 0, stream>>>(h, ht);
    k_fdmax<<<1, 256, 0, stream>>>(fd, fdm);
    k_main<<<KQ * 128, 256, 0, stream>>>(adj, fs, fd, fdm,
                                         (const unsigned short*)ht, nump, denp, jch, ns);
    k_final<<<512, 256, 0, stream>>>(nump, denp, out, KQ);
}